// Round 2
// baseline (586.320 us; speedup 1.0000x reference)
//
#include <hip/hip_runtime.h>

#define SNN_IN  8192
#define SNN_OUT 8192
#define SNN_THR 50.0f
#define BLK     512
#define VPT     (SNN_IN / 4 / BLK)   // float4 per thread per stream = 4

// One block per output row, 512 threads. All three HBM streams (states, elig,
// spike_in) are issued as 12 independent float4 loads per thread BEFORE the
// reduction, so the reduce/barrier latency overlaps the elig load latency.
// Single barrier; every thread recomputes spike from the LDS wave-sums.
__global__ __launch_bounds__(BLK) void snn_fused_kernel(
    const float* __restrict__ spike_in,   // [IN]
    const float* __restrict__ states,     // [OUT, IN]
    const float* __restrict__ v_mem,      // [OUT]
    const float* __restrict__ v_th,       // [OUT]
    const float* __restrict__ elig,       // [OUT, IN]
    const float* __restrict__ noise,      // [OUT]
    float* __restrict__ out_spikes,       // [OUT]
    float* __restrict__ out_vmem,         // [OUT]
    float* __restrict__ out_vth,          // [OUT]
    float* __restrict__ out_elig)         // [OUT, IN]
{
    const int row = blockIdx.x;
    const int tid = threadIdx.x;
    const size_t row4 = (size_t)row * (SNN_IN / 4);

    const float4* __restrict__ s4  = reinterpret_cast<const float4*>(states) + row4;
    const float4* __restrict__ e4  = reinterpret_cast<const float4*>(elig)   + row4;
    const float4* __restrict__ sp4 = reinterpret_cast<const float4*>(spike_in);

    // Per-row scalars: uniform-address broadcast loads, issued early (L2-hit).
    const float vm = v_mem[row];
    const float vt = v_th[row];
    const float nz = noise[row];

    // ---- Issue ALL loads up front: 12 independent float4 per thread ----
    float4 s[VPT], e[VPT], sp[VPT];
    #pragma unroll
    for (int j = 0; j < VPT; ++j) {
        const int idx = j * BLK + tid;   // coalesced, stride-BLK float4
        sp[j] = sp4[idx];
        s[j]  = s4[idx];
        e[j]  = e4[idx];
    }

    // ---- Masked-GEMV partial (exact: terms are 0/1 integers) ----
    float partial = 0.0f;
    #pragma unroll
    for (int j = 0; j < VPT; ++j) {
        partial += (s[j].x > SNN_THR ? sp[j].x : 0.0f)
                 + (s[j].y > SNN_THR ? sp[j].y : 0.0f)
                 + (s[j].z > SNN_THR ? sp[j].z : 0.0f)
                 + (s[j].w > SNN_THR ? sp[j].w : 0.0f);
    }

    // wave(64) butterfly reduce
    #pragma unroll
    for (int off = 32; off > 0; off >>= 1)
        partial += __shfl_down(partial, off, 64);

    __shared__ float wsum[BLK / 64];
    if ((tid & 63) == 0) wsum[tid >> 6] = partial;

    // Pin the elig payload live BEFORE the barrier so the compiler cannot
    // sink the loads past it (barrier drains vmcnt anyway — free here).
    #pragma unroll
    for (int j = 0; j < VPT; ++j)
        asm volatile("" :: "v"(e[j].x), "v"(e[j].y), "v"(e[j].z), "v"(e[j].w));

    __syncthreads();

    // Every thread recomputes the row scalars (exact fixed-order sum of 8).
    float total = 0.0f;
    #pragma unroll
    for (int w = 0; w < BLK / 64; ++w) total += wsum[w];

    const float v_new = vm * 0.8f + total + nz;
    const float spike = (v_new >= vt) ? 1.0f : 0.0f;

    if (tid == 0) {
        out_spikes[row] = spike;
        out_vmem[row]   = v_new * (1.0f - spike) * 0.2f;
        out_vth[row]    = fminf(fmaxf(vt + (spike - 0.05f) * 0.1f, 0.5f), 10.0f);
    }

    // ---- Eligibility update: compute + store only (loads already in regs) ----
    float4* __restrict__ o4 = reinterpret_cast<float4*>(out_elig) + row4;
    #pragma unroll
    for (int j = 0; j < VPT; ++j) {
        const int idx = j * BLK + tid;
        float4 r;
        r.x = fminf(fmaxf(fmaf(e[j].x, 0.95f, spike * sp[j].x), 0.0f), 5.0f);
        r.y = fminf(fmaxf(fmaf(e[j].y, 0.95f, spike * sp[j].y), 0.0f), 5.0f);
        r.z = fminf(fmaxf(fmaf(e[j].z, 0.95f, spike * sp[j].z), 0.0f), 5.0f);
        r.w = fminf(fmaxf(fmaf(e[j].w, 0.95f, spike * sp[j].w), 0.0f), 5.0f);
        o4[idx] = r;
    }
}

extern "C" void kernel_launch(void* const* d_in, const int* in_sizes, int n_in,
                              void* d_out, int out_size, void* d_ws, size_t ws_size,
                              hipStream_t stream) {
    // setup_inputs() order: spike_input, states, v_mem, v_th, elig, noise
    const float* spike_in = (const float*)d_in[0];
    const float* states   = (const float*)d_in[1];
    const float* v_mem    = (const float*)d_in[2];
    const float* v_th     = (const float*)d_in[3];
    const float* elig     = (const float*)d_in[4];
    const float* noise    = (const float*)d_in[5];

    float* out        = (float*)d_out;
    float* out_spikes = out;
    float* out_vmem   = out + SNN_OUT;
    float* out_vth    = out + 2 * SNN_OUT;
    float* out_elig   = out + 3 * SNN_OUT;

    snn_fused_kernel<<<SNN_OUT, BLK, 0, stream>>>(
        spike_in, states, v_mem, v_th, elig, noise,
        out_spikes, out_vmem, out_vth, out_elig);
}